// Round 15
// baseline (1673.583 us; speedup 1.0000x reference)
//
#include <hip/hip_runtime.h>
#include <math.h>

#define D 128
#define N_NODES 5000
#define WINDOW 10
#define N_TOTAL 50000
#define NE_INT 131072
#define NE_TMP 90000
#define NE_FWD (N_TOTAL - N_NODES)   // 45000
#define HID 1024

typedef short bf16x8 __attribute__((ext_vector_type(8)));
typedef float f32x4 __attribute__((ext_vector_type(4)));

#define SA 264   // Ain LDS row stride in shorts (256 + 8 pad)
#define SH 136   // 128 + 8 pad
#define SK 136   // 128 + 8 pad
#define SCAN_B 256

static __device__ __forceinline__ short f2bf(float f) {
    union { float f; unsigned u; } v; v.f = f;
    unsigned r = v.u + 0x7fffu + ((v.u >> 16) & 1u);   // RNE
    return (short)(r >> 16);
}
static __device__ __forceinline__ float bf2f(short s) {
    union { unsigned u; float f; } v;
    v.u = ((unsigned)(unsigned short)s) << 16;
    return v.f;
}
static __device__ __forceinline__ float lo_bf(unsigned u) {
    union { unsigned u; float f; } v; v.u = u << 16; return v.f;
}
static __device__ __forceinline__ float hi_bf(unsigned u) {
    union { unsigned u; float f; } v; v.u = u & 0xffff0000u; return v.f;
}

// ---- fast transcendentals (r13): v_exp_f32 via __expf + v_rcp_f32 ----
static __device__ __forceinline__ float fsigmoid(float x) {
    return __builtin_amdgcn_rcpf(1.f + __expf(-x));   // exp overflow benign
}
static __device__ __forceinline__ float ftanh(float x) {
    float xc = fminf(fmaxf(x, -20.f), 20.f);
    float t = __expf(2.f * xc);
    return (t - 1.f) * __builtin_amdgcn_rcpf(t + 1.f);
}

// ---------------- merged weight transpose + cvt: 8 segments in one launch ----------------
struct TcvtArgs {
    const float* in[8];
    short* out[8];
    int K[8];
    int N[8];
};
__global__ void k_tcvt8(TcvtArgs a) {
    int i = blockIdx.x * blockDim.x + threadIdx.x;
#pragma unroll
    for (int s = 0; s < 8; ++s) {
        int sz = a.K[s] * a.N[s];
        if (i < sz) {
            int n = i / a.K[s], k = i - n * a.K[s];
            a.out[s][i] = f2bf(a.in[s][(size_t)k * a.N[s] + n]);
            return;
        }
        i -= sz;
    }
}

// ---------------- init h ----------------
__global__ void k_init_h(const int* __restrict__ nodes, const float* __restrict__ embed,
                         float* __restrict__ h32, short* __restrict__ h16) {
    int i = blockIdx.x * blockDim.x + threadIdx.x;
    if (i >= N_TOTAL * D) return;
    int row = i >> 7;
    int c = i & 127;
    int n = nodes[row / WINDOW];
    float v = embed[n * D + c];
    h32[i] = v;
    h16[i] = f2bf(v);
}

// ---------------- edge builder (int only; temporal edges computed affinely in-kernel) ----------------
__global__ void k_build_int_edges(const int* __restrict__ ie, int* __restrict__ src,
                                  int* __restrict__ dst, int* __restrict__ icnt) {
    int e = blockIdx.x * blockDim.x + threadIdx.x;
    if (e >= NE_INT) return;
    int t = ie[e * 3 + 0], a = ie[e * 3 + 1], b = ie[e * 3 + 2];
    int d = t * N_NODES + b;
    src[e] = t * N_NODES + a;
    dst[e] = d;
    atomicAdd(&icnt[d], 1);
}

// ---------------- 3-kernel exclusive scan over icnt[N_TOTAL] -> rowstart ----------------
__global__ void k_scan_partial(const int* __restrict__ cnt, int* __restrict__ rowstart,
                               int* __restrict__ btot, int n) {
    __shared__ int s[SCAN_B];
    int tid = threadIdx.x;
    int i = blockIdx.x * SCAN_B + tid;
    int v = (i < n) ? cnt[i] : 0;
    s[tid] = v;
    __syncthreads();
    for (int off = 1; off < SCAN_B; off <<= 1) {
        int x = (tid >= off) ? s[tid - off] : 0;
        __syncthreads();
        s[tid] += x;
        __syncthreads();
    }
    if (i < n) rowstart[i] = s[tid] - v;   // block-local exclusive
    if (tid == SCAN_B - 1) btot[blockIdx.x] = s[tid];
}

__global__ void k_scan_block(int* __restrict__ btot, int nb) {
    __shared__ int s[SCAN_B];
    int tid = threadIdx.x;
    int v = (tid < nb) ? btot[tid] : 0;
    s[tid] = v;
    __syncthreads();
    for (int off = 1; off < SCAN_B; off <<= 1) {
        int x = (tid >= off) ? s[tid - off] : 0;
        __syncthreads();
        s[tid] += x;
        __syncthreads();
    }
    if (tid < nb) btot[tid] = s[tid] - v;  // exclusive block offsets
}

__global__ void k_scan_add(int* __restrict__ rowstart, const int* __restrict__ btot,
                           int* __restrict__ cursor, int n, int total) {
    int i = blockIdx.x * blockDim.x + threadIdx.x;
    if (i < n) {
        int v = rowstart[i] + btot[i >> 8];
        rowstart[i] = v;
        cursor[i] = v;
    }
    if (i == 0) rowstart[n] = total;
}

// eidx[p] = edge at CSR slot p (dst-sorted). msg processes slots in order -> dense m store.
__global__ void k_fill_csr(const int* __restrict__ dst, int nE, int* __restrict__ cursor,
                           int* __restrict__ eidx) {
    int e = blockIdx.x * blockDim.x + threadIdx.x;
    if (e >= nE) return;
    int p = atomicAdd(&cursor[dst[e]], 1);
    eidx[p] = e;
}

// ---------------- degree-sort of rows (counting sort, 64 bins) ----------------
// rperm groups equal-degree rows so each gru wave's 16 rows run the SAME gather trip
// count (was: wave runs to max-degree of 16 Poisson(2.6) rows ~ 2.7x predicated waste).
__global__ void k_deg_hist(const int* __restrict__ rowstart, int* __restrict__ hist) {
    int row = blockIdx.x * blockDim.x + threadIdx.x;
    if (row >= N_TOTAL) return;
    int d = rowstart[row + 1] - rowstart[row];
    atomicAdd(&hist[d > 63 ? 63 : d], 1);
}
__global__ void k_deg_scan(const int* __restrict__ hist, int* __restrict__ cur2) {
    if (threadIdx.x == 0) {
        int s = 0;
        for (int i = 0; i < 64; ++i) { cur2[i] = s; s += hist[i]; }
    }
}
__global__ void k_deg_scatter(const int* __restrict__ rowstart, int* __restrict__ cur2,
                              int* __restrict__ rperm) {
    int row = blockIdx.x * blockDim.x + threadIdx.x;
    if (row >= N_TOTAL) return;
    int d = rowstart[row + 1] - rowstart[row];
    int p = atomicAdd(&cur2[d > 63 ? 63 : d], 1);
    rperm[p] = row;
}

// ---------------- fused message MLP (MFMA), 128-slot blocks, W register-prefetch ----------------
// r12/r13 proven structure (183us int): CSR-ordered slots + W1/W2 register prefetch.
__global__ void __launch_bounds__(256, 1) k_msg_mfma(
    const short* __restrict__ h16, const int* __restrict__ eidx,
    const int* __restrict__ src, const int* __restrict__ dst,
    int nE, int tmpMode,
    const short* __restrict__ W1T, const float* __restrict__ b1,
    const short* __restrict__ W2T, const float* __restrict__ b2,
    short* __restrict__ m)
{
    __shared__ short Ain[128 * SA];   // [slot][0:256) = [h[src] | h[dst]] bf16 (66 KiB)
    __shared__ short Hid[128 * SH];   // [slot][128] hidden chunk bf16 (34 KiB)

    int t = threadIdx.x;
    int p0 = blockIdx.x * 128;

    // ---- gather: 2 threads/slot; q=0 loads src half, q=1 loads dst half ----
    {
        int r = t >> 1, q = t & 1;
        int p = p0 + r;
        int pc = (p < nE) ? p : (nE - 1);
        int s, d;
        if (tmpMode) {
            if (pc < NE_FWD) { s = pc; d = pc + N_NODES; }
            else { int qq = pc - NE_FWD; s = qq + N_NODES; d = qq; }
        } else {
            int e = eidx[pc];
            s = src[e];
            d = dst[e];
        }
        uint4* ao = (uint4*)(Ain + r * SA);
        if (q == 0) {
            const uint4* ps = (const uint4*)(h16 + (size_t)s * D);
#pragma unroll
            for (int i = 0; i < 16; ++i) ao[i] = ps[i];
        } else {
            const uint4* pd = (const uint4*)(h16 + (size_t)d * D);
#pragma unroll
            for (int i = 0; i < 16; ++i) ao[16 + i] = pd[i];
        }
    }
    __syncthreads();

    int w = t >> 6, lane = t & 63;
    int lm = lane & 15, lk = lane >> 4;

    // persistent GEMM2 accumulators: wave w owns out channels [32w, 32w+32) x 128 slots
    f32x4 c2[2][8];
#pragma unroll
    for (int cs = 0; cs < 2; ++cs) {
        int out0 = w * 32 + cs * 16 + lk * 4;
#pragma unroll
        for (int et = 0; et < 8; ++et)
#pragma unroll
            for (int rg = 0; rg < 4; ++rg) c2[cs][et][rg] = b2[out0 + rg];
    }

    // prologue: W1 fragments for chunk 0 into registers
    bf16x8 w1a[8], w1b[8];
#pragma unroll
    for (int kk = 0; kk < 8; ++kk) {
        int ko = kk * 32 + lk * 8;
        w1a[kk] = *(const bf16x8*)(W1T + (size_t)(w * 32 + lm) * 256 + ko);
        w1b[kk] = *(const bf16x8*)(W1T + (size_t)(w * 32 + 16 + lm) * 256 + ko);
    }

    for (int hc = 0; hc < 8; ++hc) {
        // prefetch W2(hc): consumed after the barrier; latency covered by GEMM1 below
        bf16x8 w2a[4], w2b[4];
#pragma unroll
        for (int kk = 0; kk < 4; ++kk) {
            int ko = kk * 32 + lk * 8;
            w2a[kk] = *(const bf16x8*)(W2T + (size_t)(w * 32 + lm) * 1024 + hc * 128 + ko);
            w2b[kk] = *(const bf16x8*)(W2T + (size_t)(w * 32 + 16 + lm) * 1024 + hc * 128 + ko);
        }

        // GEMM1: c1 = Ain @ W1 chunk (W1 fragments already in registers)
        f32x4 c1[2][8];
#pragma unroll
        for (int cs = 0; cs < 2; ++cs) {
            int ch0 = hc * 128 + w * 32 + cs * 16 + lk * 4;
#pragma unroll
            for (int et = 0; et < 8; ++et)
#pragma unroll
                for (int rg = 0; rg < 4; ++rg) c1[cs][et][rg] = b1[ch0 + rg];
        }
#pragma unroll
        for (int kk = 0; kk < 8; ++kk) {
            int ko = kk * 32 + lk * 8;
            bf16x8 bf[8];
#pragma unroll
            for (int et = 0; et < 8; ++et)
                bf[et] = *(const bf16x8*)(Ain + (et * 16 + lm) * SA + ko);
#pragma unroll
            for (int et = 0; et < 8; ++et) {
                c1[0][et] = __builtin_amdgcn_mfma_f32_16x16x32_bf16(w1a[kk], bf[et], c1[0][et], 0, 0, 0);
                c1[1][et] = __builtin_amdgcn_mfma_f32_16x16x32_bf16(w1b[kk], bf[et], c1[1][et], 0, 0, 0);
            }
        }

        // prefetch W1(hc+1): latency covered by Hid-write + barrier + GEMM2
        if (hc < 7) {
#pragma unroll
            for (int kk = 0; kk < 8; ++kk) {
                int ko = kk * 32 + lk * 8;
                w1a[kk] = *(const bf16x8*)(W1T + (size_t)((hc + 1) * 128 + w * 32 + lm) * 256 + ko);
                w1b[kk] = *(const bf16x8*)(W1T + (size_t)((hc + 1) * 128 + w * 32 + 16 + lm) * 256 + ko);
            }
        }

        __syncthreads();   // all waves done reading Hid (GEMM2 of hc-1)
        // write Hid = relu(c1): wave w fills channels [32w, +32) for all 128 slots
#pragma unroll
        for (int cs = 0; cs < 2; ++cs) {
            int ch_in = w * 32 + cs * 16 + lk * 4;
#pragma unroll
            for (int et = 0; et < 8; ++et) {
                int edge = et * 16 + lm;
                short4 sv;
                sv.x = f2bf(fmaxf(c1[cs][et][0], 0.f));
                sv.y = f2bf(fmaxf(c1[cs][et][1], 0.f));
                sv.z = f2bf(fmaxf(c1[cs][et][2], 0.f));
                sv.w = f2bf(fmaxf(c1[cs][et][3], 0.f));
                *(short4*)(Hid + edge * SH + ch_in) = sv;
            }
        }
        __syncthreads();   // Hid(hc) visible

        // GEMM2: accumulate m += Hid(hc) @ W2 chunk (W2 fragments already in registers)
#pragma unroll
        for (int kk = 0; kk < 4; ++kk) {
            int ko = kk * 32 + lk * 8;
            bf16x8 bf[8];
#pragma unroll
            for (int et = 0; et < 8; ++et)
                bf[et] = *(const bf16x8*)(Hid + (et * 16 + lm) * SH + ko);
#pragma unroll
            for (int et = 0; et < 8; ++et) {
                c2[0][et] = __builtin_amdgcn_mfma_f32_16x16x32_bf16(w2a[kk], bf[et], c2[0][et], 0, 0, 0);
                c2[1][et] = __builtin_amdgcn_mfma_f32_16x16x32_bf16(w2b[kk], bf[et], c2[1][et], 0, 0, 0);
            }
        }
    }

    // ---- bf16 store: m[p][ch] = relu(msg) -- dense, fully coalesced per block ----
#pragma unroll
    for (int et = 0; et < 8; ++et) {
        int edge = et * 16 + lm;
        int p = p0 + edge;
        if (p >= nE) continue;
        short* rowp = m + (size_t)p * 128;
#pragma unroll
        for (int cs = 0; cs < 2; ++cs) {
            int out0 = w * 32 + cs * 16 + lk * 4;
            short4 sv;
            sv.x = f2bf(fmaxf(c2[cs][et][0], 0.f));
            sv.y = f2bf(fmaxf(c2[cs][et][1], 0.f));
            sv.z = f2bf(fmaxf(c2[cs][et][2], 0.f));
            sv.w = f2bf(fmaxf(c2[cs][et][3], 0.f));
            *(short4*)(rowp + out0) = sv;
        }
    }
}

// ---------------- fused seg-mean (CSR or temporal) + GRU (MFMA), in place ----------------
// mode 0: rows processed in degree-sorted order (rperm) -> uniform gather trip count
// per wave (kills the 2.7x max-vs-mean predicated waste + straggler tail).
// mode 1: temporal (affine, rperm=null). 34.8 KB LDS, 4 blocks/CU. r14 hold-prefetch kept.
__global__ void __launch_bounds__(256, 4) k_gru_mfma(
    const short* __restrict__ m, const int* __restrict__ rowstart,
    const int* __restrict__ rperm, int mode,
    float* __restrict__ h32, short* __restrict__ h16,
    const short* __restrict__ WT, const short* __restrict__ UT,
    const float* __restrict__ b)
{
    __shared__ short Ax[64 * SK];
    __shared__ short Hx[64 * SK];
    int t = threadIdx.x;
    int r0 = blockIdx.x * 64;

    {
        int r = t >> 2, q = t & 3;
        int slot = r0 + r;
        int sc = (slot < N_TOTAL) ? slot : (N_TOTAL - 1);
        int rowg = rperm ? rperm[sc] : sc;
        const uint4* hp = (const uint4*)(h16 + (size_t)rowg * D);
        uint4* hxo = (uint4*)(Hx + r * SK);
#pragma unroll
        for (int i = 0; i < 4; ++i) hxo[q * 4 + i] = hp[q * 4 + i];

        float acc[32];
#pragma unroll
        for (int i = 0; i < 32; ++i) acc[i] = 0.f;
        int deg = 0;
        if (slot < N_TOTAL) {
            if (mode == 0) {
                int s0 = rowstart[rowg], s1 = rowstart[rowg + 1];
                deg = s1 - s0;
                for (int p = s0; p < s1; ++p) {
                    const uint4* mp = (const uint4*)(m + (size_t)p * 128 + q * 32);
#pragma unroll
                    for (int i = 0; i < 4; ++i) {
                        uint4 v = mp[i];
                        unsigned ua[4] = {v.x, v.y, v.z, v.w};
#pragma unroll
                        for (int j = 0; j < 4; ++j) {
                            acc[i * 8 + 2 * j]     += lo_bf(ua[j]);
                            acc[i * 8 + 2 * j + 1] += hi_bf(ua[j]);
                        }
                    }
                }
            } else {
                if (rowg >= N_NODES) {   // fwd edge e = rowg - N_NODES
                    const uint4* mp = (const uint4*)(m + (size_t)(rowg - N_NODES) * 128 + q * 32);
                    ++deg;
#pragma unroll
                    for (int i = 0; i < 4; ++i) {
                        uint4 v = mp[i];
                        unsigned ua[4] = {v.x, v.y, v.z, v.w};
#pragma unroll
                        for (int j = 0; j < 4; ++j) {
                            acc[i * 8 + 2 * j]     += lo_bf(ua[j]);
                            acc[i * 8 + 2 * j + 1] += hi_bf(ua[j]);
                        }
                    }
                }
                if (rowg < NE_FWD) {     // bwd edge e = NE_FWD + rowg
                    const uint4* mp = (const uint4*)(m + (size_t)(NE_FWD + rowg) * 128 + q * 32);
                    ++deg;
#pragma unroll
                    for (int i = 0; i < 4; ++i) {
                        uint4 v = mp[i];
                        unsigned ua[4] = {v.x, v.y, v.z, v.w};
#pragma unroll
                        for (int j = 0; j < 4; ++j) {
                            acc[i * 8 + 2 * j]     += lo_bf(ua[j]);
                            acc[i * 8 + 2 * j + 1] += hi_bf(ua[j]);
                        }
                    }
                }
            }
        }
        float inv = (deg > 0) ? __builtin_amdgcn_rcpf((float)deg) : 0.f;
        uint4* axp = (uint4*)(Ax + r * SK + q * 32);
#pragma unroll
        for (int i = 0; i < 4; ++i) {
            union { uint4 u; short s[8]; } pk;
#pragma unroll
            for (int j = 0; j < 8; ++j) pk.s[j] = f2bf(acc[i * 8 + j] * inv);
            axp[i] = pk.u;
        }
    }
    __syncthreads();

    int w = t >> 6, lane = t & 63;
    int lm = lane & 15, lk = lane >> 4;

    // row mapping for this thread's 4 output rows (constant across g)
    int slotw[4], roww[4];
#pragma unroll
    for (int rg = 0; rg < 4; ++rg) {
        slotw[rg] = r0 + w * 16 + lk * 4 + rg;
        int sc = (slotw[rg] < N_TOTAL) ? slotw[rg] : (N_TOTAL - 1);
        roww[rg] = rperm ? rperm[sc] : sc;
    }

    for (int g = 0; g < 8; ++g) {
        int ch = g * 16 + lm;

        // prefetch hold = h32[row][ch]: issues before the MFMA cluster (r14)
        float hold[4];
#pragma unroll
        for (int rg = 0; rg < 4; ++rg)
            hold[rg] = h32[(size_t)roww[rg] * D + ch];

        f32x4 cxz, cxr, cxh, chz, chr_, chh;
#pragma unroll
        for (int rg = 0; rg < 4; ++rg) {
            cxz[rg] = b[ch];        chz[rg] = b[384 + ch];
            cxr[rg] = b[128 + ch];  chr_[rg] = b[384 + 128 + ch];
            cxh[rg] = b[256 + ch];  chh[rg] = b[384 + 256 + ch];
        }
#pragma unroll
        for (int kk = 0; kk < 4; ++kk) {
            int ko = kk * 32 + lk * 8;
            bf16x8 ax = *(const bf16x8*)(Ax + (w * 16 + lm) * SK + ko);
            bf16x8 hx = *(const bf16x8*)(Hx + (w * 16 + lm) * SK + ko);
            bf16x8 bz = *(const bf16x8*)(WT + (size_t)(ch) * 128 + ko);
            bf16x8 br = *(const bf16x8*)(WT + (size_t)(128 + ch) * 128 + ko);
            bf16x8 bh = *(const bf16x8*)(WT + (size_t)(256 + ch) * 128 + ko);
            bf16x8 uz = *(const bf16x8*)(UT + (size_t)(ch) * 128 + ko);
            bf16x8 ur = *(const bf16x8*)(UT + (size_t)(128 + ch) * 128 + ko);
            bf16x8 uh = *(const bf16x8*)(UT + (size_t)(256 + ch) * 128 + ko);
            cxz = __builtin_amdgcn_mfma_f32_16x16x32_bf16(ax, bz, cxz, 0, 0, 0);
            cxr = __builtin_amdgcn_mfma_f32_16x16x32_bf16(ax, br, cxr, 0, 0, 0);
            cxh = __builtin_amdgcn_mfma_f32_16x16x32_bf16(ax, bh, cxh, 0, 0, 0);
            chz = __builtin_amdgcn_mfma_f32_16x16x32_bf16(hx, uz, chz, 0, 0, 0);
            chr_ = __builtin_amdgcn_mfma_f32_16x16x32_bf16(hx, ur, chr_, 0, 0, 0);
            chh = __builtin_amdgcn_mfma_f32_16x16x32_bf16(hx, uh, chh, 0, 0, 0);
        }
#pragma unroll
        for (int rg = 0; rg < 4; ++rg) {
            if (slotw[rg] >= N_TOTAL) continue;
            float z = fsigmoid(cxz[rg] + chz[rg]);
            float r_ = fsigmoid(cxr[rg] + chr_[rg]);
            float hcv = ftanh(cxh[rg] + r_ * chh[rg]);
            size_t idx = (size_t)roww[rg] * D + ch;
            float hnew = z * hold[rg] + (1.f - z) * hcv;
            h32[idx] = hnew;
            h16[idx] = f2bf(hnew);
        }
    }
}

// ---------------- generic MFMA GEMM: C = relu(A16 @ B + bias) ----------------
__global__ void __launch_bounds__(256, 4) k_ro_mfma(
    const short* __restrict__ A16, const short* __restrict__ BT,
    const float* __restrict__ bias, float* __restrict__ C32, short* __restrict__ C16,
    int M, int N, int K)
{
    __shared__ short As[64 * SK];
    int t = threadIdx.x;
    int mb = blockIdx.y * 64;
    int nb = blockIdx.x * 128;
    int w = t >> 6, lane = t & 63;
    int lm = lane & 15, lk = lane >> 4;

    f32x4 acc[8];
#pragma unroll
    for (int nt = 0; nt < 8; ++nt) {
        float bv = bias[nb + nt * 16 + lm];
        acc[nt][0] = bv; acc[nt][1] = bv; acc[nt][2] = bv; acc[nt][3] = bv;
    }

    for (int kc = 0; kc < K; kc += 128) {
        __syncthreads();
        {
            int r = t >> 2, q = t & 3;
            int row = mb + r;
            int rc = (row < M) ? row : (M - 1);
            const uint4* ap = (const uint4*)(A16 + (size_t)rc * K + kc);
            uint4* ao = (uint4*)(As + r * SK);
#pragma unroll
            for (int i = 0; i < 4; ++i) ao[i * 4 + q] = ap[i * 4 + q];
        }
        __syncthreads();
#pragma unroll
        for (int kk = 0; kk < 4; ++kk) {
            int ko = kk * 32 + lk * 8;
            bf16x8 a = *(const bf16x8*)(As + (w * 16 + lm) * SK + ko);
#pragma unroll
            for (int nt = 0; nt < 8; ++nt) {
                bf16x8 bfr = *(const bf16x8*)(BT + (size_t)(nb + nt * 16 + lm) * K + kc + ko);
                acc[nt] = __builtin_amdgcn_mfma_f32_16x16x32_bf16(a, bfr, acc[nt], 0, 0, 0);
            }
        }
    }
#pragma unroll
    for (int nt = 0; nt < 8; ++nt) {
        int col = nb + nt * 16 + lm;
#pragma unroll
        for (int rg = 0; rg < 4; ++rg) {
            int row = mb + w * 16 + lk * 4 + rg;
            if (row >= M) continue;
            float v = fmaxf(acc[nt][rg], 0.f);
            if (C32) C32[(size_t)row * N + col] = v;
            if (C16) C16[(size_t)row * N + col] = f2bf(v);
        }
    }
}

// ---------------- final 512x10 logits + softmax ----------------
__global__ void __launch_bounds__(64) k_logits_softmax(
    const float* __restrict__ r2, const float* __restrict__ W3,
    const float* __restrict__ b3, float* __restrict__ out)
{
    int row = blockIdx.x;
    int t = threadIdx.x;
    float p[10];
#pragma unroll
    for (int j = 0; j < 10; ++j) p[j] = 0.f;
    for (int k = t; k < 512; k += 64) {
        float v = r2[(size_t)row * 512 + k];
#pragma unroll
        for (int j = 0; j < 10; ++j) p[j] += v * W3[k * 10 + j];
    }
#pragma unroll
    for (int j = 0; j < 10; ++j) {
        float s = p[j];
        for (int off = 32; off > 0; off >>= 1) s += __shfl_down(s, off);
        p[j] = s;
    }
    if (t == 0) {
        float mx = -1e30f;
#pragma unroll
        for (int j = 0; j < 10; ++j) { p[j] += b3[j]; mx = fmaxf(mx, p[j]); }
        float sum = 0.f;
#pragma unroll
        for (int j = 0; j < 10; ++j) { p[j] = __expf(p[j] - mx); sum += p[j]; }
        float inv = 1.f / sum;
#pragma unroll
        for (int j = 0; j < 10; ++j) out[(size_t)row * 10 + j] = p[j] * inv;
    }
}

extern "C" void kernel_launch(void* const* d_in, const int* in_sizes, int n_in,
                              void* d_out, int out_size, void* d_ws, size_t ws_size,
                              hipStream_t stream)
{
    const int*   ie    = (const int*)d_in[0];
    const int*   nodes = (const int*)d_in[1];
    const float* embed = (const float*)d_in[2];
    const float* mW1   = (const float*)d_in[3];
    const float* mb1   = (const float*)d_in[4];
    const float* mW2   = (const float*)d_in[5];
    const float* mb2   = (const float*)d_in[6];
    const float* giW   = (const float*)d_in[7];
    const float* giU   = (const float*)d_in[8];
    const float* gib   = (const float*)d_in[9];
    const float* gtW   = (const float*)d_in[10];
    const float* gtU   = (const float*)d_in[11];
    const float* gtb   = (const float*)d_in[12];
    const float* rW1   = (const float*)d_in[13];
    const float* rb1   = (const float*)d_in[14];
    const float* rW2   = (const float*)d_in[15];
    const float* rb2   = (const float*)d_in[16];
    const float* rW3   = (const float*)d_in[17];
    const float* rb3   = (const float*)d_in[18];
    float* out = (float*)d_out;

    char* ws = (char*)d_ws;
    size_t off = 0;
    auto alloc = [&](size_t bytes) {
        void* p = ws + off;
        off += (bytes + 255) & ~(size_t)255;
        return p;
    };
    float* h32   = (float*)alloc((size_t)N_TOTAL * D * 4);
    short* h16   = (short*)alloc((size_t)N_TOTAL * D * 2);
    short* m     = (short*)alloc((size_t)NE_INT * 128 * 2);   // edge messages, bf16
    int*   icnt  = (int*)alloc((size_t)N_TOTAL * 4);
    int*   rowst = (int*)alloc((size_t)(N_TOTAL + 1) * 4);
    int*   btot  = (int*)alloc(256 * 4);
    int*   curs  = (int*)alloc((size_t)N_TOTAL * 4);
    int*   eidx  = (int*)alloc((size_t)NE_INT * 4);
    int*   srcA  = (int*)alloc((size_t)NE_INT * 4);
    int*   dstA  = (int*)alloc((size_t)NE_INT * 4);
    int*   dhist = (int*)alloc(64 * 4);
    int*   dcur  = (int*)alloc(64 * 4);
    int*   rperm = (int*)alloc((size_t)N_TOTAL * 4);
    short* mW1T  = (short*)alloc((size_t)HID * 256 * 2);
    short* mW2T  = (short*)alloc((size_t)D * HID * 2);
    short* giWT  = (short*)alloc((size_t)384 * D * 2);
    short* giUT  = (short*)alloc((size_t)384 * D * 2);
    short* gtWT  = (short*)alloc((size_t)384 * D * 2);
    short* gtUT  = (short*)alloc((size_t)384 * D * 2);
    short* rW1T  = (short*)alloc((size_t)HID * D * 2);
    short* rW2T  = (short*)alloc((size_t)512 * HID * 2);
    short* r1_16 = (short*)alloc((size_t)N_NODES * HID * 2);
    float* r2_32 = (float*)alloc((size_t)N_NODES * 512 * 4);

    // weight repack: 8 transposes in ONE launch
    {
        TcvtArgs a;
        a.in[0] = mW1; a.out[0] = mW1T; a.K[0] = 256; a.N[0] = HID;
        a.in[1] = mW2; a.out[1] = mW2T; a.K[1] = HID; a.N[1] = D;
        a.in[2] = giW; a.out[2] = giWT; a.K[2] = D;   a.N[2] = 384;
        a.in[3] = giU; a.out[3] = giUT; a.K[3] = D;   a.N[3] = 384;
        a.in[4] = gtW; a.out[4] = gtWT; a.K[4] = D;   a.N[4] = 384;
        a.in[5] = gtU; a.out[5] = gtUT; a.K[5] = D;   a.N[5] = 384;
        a.in[6] = rW1; a.out[6] = rW1T; a.K[6] = D;   a.N[6] = HID;
        a.in[7] = rW2; a.out[7] = rW2T; a.K[7] = HID; a.N[7] = 512;
        int total = 256 * HID + HID * D + 4 * (D * 384) + D * HID + HID * 512;
        k_tcvt8<<<(total + 255) / 256, 256, 0, stream>>>(a);
    }

    // init + CSR build (int edges static across iterations)
    hipMemsetAsync(icnt, 0, (size_t)N_TOTAL * 4, stream);
    hipMemsetAsync(dhist, 0, 64 * 4, stream);
    k_init_h<<<(N_TOTAL * D + 255) / 256, 256, 0, stream>>>(nodes, embed, h32, h16);
    k_build_int_edges<<<(NE_INT + 255) / 256, 256, 0, stream>>>(ie, srcA, dstA, icnt);
    int nb = (N_TOTAL + SCAN_B - 1) / SCAN_B;   // 196
    k_scan_partial<<<nb, SCAN_B, 0, stream>>>(icnt, rowst, btot, N_TOTAL);
    k_scan_block<<<1, SCAN_B, 0, stream>>>(btot, nb);
    k_scan_add<<<nb, SCAN_B, 0, stream>>>(rowst, btot, curs, N_TOTAL, NE_INT);
    k_fill_csr<<<(NE_INT + 255) / 256, 256, 0, stream>>>(dstA, NE_INT, curs, eidx);
    // degree-sorted row permutation for gru mode 0 (counting sort, 64 bins)
    k_deg_hist<<<(N_TOTAL + 255) / 256, 256, 0, stream>>>(rowst, dhist);
    k_deg_scan<<<1, 64, 0, stream>>>(dhist, dcur);
    k_deg_scatter<<<(N_TOTAL + 255) / 256, 256, 0, stream>>>(rowst, dcur, rperm);

    int gmsgA = (NE_INT + 127) / 128;   // 1024
    int gmsgT = (NE_TMP + 127) / 128;   // 704
    int ggru = (N_TOTAL + 63) / 64;     // 782
    for (int it = 0; it < 2; ++it) {
        // int pass: CSR-ordered processing -> dense m store, dst-local gather
        k_msg_mfma<<<gmsgA, 256, 0, stream>>>(h16, eidx, srcA, dstA, NE_INT, 0, mW1T, mb1, mW2T, mb2, m);
        k_gru_mfma<<<ggru, 256, 0, stream>>>(m, rowst, rperm, 0, h32, h16, giWT, giUT, gib);

        // temporal pass: affine src/dst in-kernel, identity slot order
        k_msg_mfma<<<gmsgT, 256, 0, stream>>>(h16, (const int*)nullptr, (const int*)nullptr,
                                              (const int*)nullptr, NE_TMP, 1, mW1T, mb1, mW2T, mb2, m);
        k_gru_mfma<<<ggru, 256, 0, stream>>>(m, rowst, (const int*)nullptr, 1, h32, h16, gtWT, gtUT, gtb);
    }

    // readout
    dim3 g1(HID / 128, (N_NODES + 63) / 64);
    k_ro_mfma<<<g1, 256, 0, stream>>>(h16, rW1T, rb1, (float*)nullptr, r1_16, N_NODES, HID, D);
    dim3 g2(512 / 128, (N_NODES + 63) / 64);
    k_ro_mfma<<<g2, 256, 0, stream>>>(r1_16, rW2T, rb2, r2_32, (short*)nullptr, N_NODES, 512, HID);
    k_logits_softmax<<<N_NODES, 64, 0, stream>>>(r2_32, rW3, rb3, out);
}

// Round 16
// 1218.040 us; speedup vs baseline: 1.3740x; 1.3740x over previous
//
#include <hip/hip_runtime.h>
#include <math.h>

#define D 128
#define N_NODES 5000
#define WINDOW 10
#define N_TOTAL 50000
#define NE_INT 131072
#define NE_TMP 90000
#define NE_FWD (N_TOTAL - N_NODES)   // 45000
#define HID 1024

typedef short bf16x8 __attribute__((ext_vector_type(8)));
typedef float f32x4 __attribute__((ext_vector_type(4)));

#define SA 264   // Ain LDS row stride in shorts (256 + 8 pad)
#define SH 136   // 128 + 8 pad
#define SK 136   // 128 + 8 pad
#define SCAN_B 256

static __device__ __forceinline__ short f2bf(float f) {
    union { float f; unsigned u; } v; v.f = f;
    unsigned r = v.u + 0x7fffu + ((v.u >> 16) & 1u);   // RNE
    return (short)(r >> 16);
}
static __device__ __forceinline__ float bf2f(short s) {
    union { unsigned u; float f; } v;
    v.u = ((unsigned)(unsigned short)s) << 16;
    return v.f;
}
static __device__ __forceinline__ float lo_bf(unsigned u) {
    union { unsigned u; float f; } v; v.u = u << 16; return v.f;
}
static __device__ __forceinline__ float hi_bf(unsigned u) {
    union { unsigned u; float f; } v; v.u = u & 0xffff0000u; return v.f;
}

// ---- fast transcendentals (r13): v_exp_f32 via __expf + v_rcp_f32 ----
static __device__ __forceinline__ float fsigmoid(float x) {
    return __builtin_amdgcn_rcpf(1.f + __expf(-x));   // exp overflow benign
}
static __device__ __forceinline__ float ftanh(float x) {
    float xc = fminf(fmaxf(x, -20.f), 20.f);
    float t = __expf(2.f * xc);
    return (t - 1.f) * __builtin_amdgcn_rcpf(t + 1.f);
}

// ---------------- merged weight transpose + cvt: 8 segments in one launch ----------------
struct TcvtArgs {
    const float* in[8];
    short* out[8];
    int K[8];
    int N[8];
};
__global__ void k_tcvt8(TcvtArgs a) {
    int i = blockIdx.x * blockDim.x + threadIdx.x;
#pragma unroll
    for (int s = 0; s < 8; ++s) {
        int sz = a.K[s] * a.N[s];
        if (i < sz) {
            int n = i / a.K[s], k = i - n * a.K[s];
            a.out[s][i] = f2bf(a.in[s][(size_t)k * a.N[s] + n]);
            return;
        }
        i -= sz;
    }
}

// ---------------- init h ----------------
__global__ void k_init_h(const int* __restrict__ nodes, const float* __restrict__ embed,
                         float* __restrict__ h32, short* __restrict__ h16) {
    int i = blockIdx.x * blockDim.x + threadIdx.x;
    if (i >= N_TOTAL * D) return;
    int row = i >> 7;
    int c = i & 127;
    int n = nodes[row / WINDOW];
    float v = embed[n * D + c];
    h32[i] = v;
    h16[i] = f2bf(v);
}

// ---------------- edge builder (int only; temporal edges computed affinely in-kernel) ----------------
__global__ void k_build_int_edges(const int* __restrict__ ie, int* __restrict__ src,
                                  int* __restrict__ dst, int* __restrict__ icnt) {
    int e = blockIdx.x * blockDim.x + threadIdx.x;
    if (e >= NE_INT) return;
    int t = ie[e * 3 + 0], a = ie[e * 3 + 1], b = ie[e * 3 + 2];
    int d = t * N_NODES + b;
    src[e] = t * N_NODES + a;
    dst[e] = d;
    atomicAdd(&icnt[d], 1);
}

// ---------------- 3-kernel exclusive scan over icnt[N_TOTAL] -> rowstart ----------------
__global__ void k_scan_partial(const int* __restrict__ cnt, int* __restrict__ rowstart,
                               int* __restrict__ btot, int n) {
    __shared__ int s[SCAN_B];
    int tid = threadIdx.x;
    int i = blockIdx.x * SCAN_B + tid;
    int v = (i < n) ? cnt[i] : 0;
    s[tid] = v;
    __syncthreads();
    for (int off = 1; off < SCAN_B; off <<= 1) {
        int x = (tid >= off) ? s[tid - off] : 0;
        __syncthreads();
        s[tid] += x;
        __syncthreads();
    }
    if (i < n) rowstart[i] = s[tid] - v;   // block-local exclusive
    if (tid == SCAN_B - 1) btot[blockIdx.x] = s[tid];
}

__global__ void k_scan_block(int* __restrict__ btot, int nb) {
    __shared__ int s[SCAN_B];
    int tid = threadIdx.x;
    int v = (tid < nb) ? btot[tid] : 0;
    s[tid] = v;
    __syncthreads();
    for (int off = 1; off < SCAN_B; off <<= 1) {
        int x = (tid >= off) ? s[tid - off] : 0;
        __syncthreads();
        s[tid] += x;
        __syncthreads();
    }
    if (tid < nb) btot[tid] = s[tid] - v;  // exclusive block offsets
}

__global__ void k_scan_add(int* __restrict__ rowstart, const int* __restrict__ btot,
                           int* __restrict__ cursor, int n, int total) {
    int i = blockIdx.x * blockDim.x + threadIdx.x;
    if (i < n) {
        int v = rowstart[i] + btot[i >> 8];
        rowstart[i] = v;
        cursor[i] = v;
    }
    if (i == 0) rowstart[n] = total;
}

// eidx[p] = edge at CSR slot p (dst-sorted). msg processes slots in order -> dense m store.
__global__ void k_fill_csr(const int* __restrict__ dst, int nE, int* __restrict__ cursor,
                           int* __restrict__ eidx) {
    int e = blockIdx.x * blockDim.x + threadIdx.x;
    if (e >= nE) return;
    int p = atomicAdd(&cursor[dst[e]], 1);
    eidx[p] = e;
}

// ---------------- degree-sort of rows (counting sort, 64 bins) ----------------
// r15's version did 50000 global atomicAdds onto ~6 hot bins -> 227us/dispatch of pure
// atomic serialization. r16: per-block LDS histogram + ONE global atomicAdd per
// (block,bin) -> contention drops ~256x; both kernels ~5us.
__global__ void k_deg_hist(const int* __restrict__ rowstart, int* __restrict__ hist) {
    __shared__ int lh[64];
    int tid = threadIdx.x;
    if (tid < 64) lh[tid] = 0;
    __syncthreads();
    int row = blockIdx.x * blockDim.x + tid;
    if (row < N_TOTAL) {
        int d = rowstart[row + 1] - rowstart[row];
        atomicAdd(&lh[d > 63 ? 63 : d], 1);
    }
    __syncthreads();
    if (tid < 64 && lh[tid] > 0) atomicAdd(&hist[tid], lh[tid]);
}
__global__ void k_deg_scan(const int* __restrict__ hist, int* __restrict__ cur2) {
    if (threadIdx.x == 0) {
        int s = 0;
        for (int i = 0; i < 64; ++i) { cur2[i] = s; s += hist[i]; }
    }
}
__global__ void k_deg_scatter(const int* __restrict__ rowstart, int* __restrict__ cur2,
                              int* __restrict__ rperm) {
    __shared__ int lh[64];      // local per-bin count
    __shared__ int lbase[64];   // global base reserved for this block's bin entries
    int tid = threadIdx.x;
    if (tid < 64) lh[tid] = 0;
    __syncthreads();
    int row = blockIdx.x * blockDim.x + tid;
    int d = 0, loff = 0;
    bool valid = (row < N_TOTAL);
    if (valid) {
        d = rowstart[row + 1] - rowstart[row];
        if (d > 63) d = 63;
        loff = atomicAdd(&lh[d], 1);          // LDS atomic: fast
    }
    __syncthreads();
    if (tid < 64 && lh[tid] > 0) lbase[tid] = atomicAdd(&cur2[tid], lh[tid]);
    __syncthreads();
    if (valid) rperm[lbase[d] + loff] = row;  // bijection; within-bin order arbitrary
}

// ---------------- fused message MLP (MFMA), 128-slot blocks, W register-prefetch ----------------
// r12/r13 proven structure (183us int): CSR-ordered slots + W1/W2 register prefetch.
__global__ void __launch_bounds__(256, 1) k_msg_mfma(
    const short* __restrict__ h16, const int* __restrict__ eidx,
    const int* __restrict__ src, const int* __restrict__ dst,
    int nE, int tmpMode,
    const short* __restrict__ W1T, const float* __restrict__ b1,
    const short* __restrict__ W2T, const float* __restrict__ b2,
    short* __restrict__ m)
{
    __shared__ short Ain[128 * SA];   // [slot][0:256) = [h[src] | h[dst]] bf16 (66 KiB)
    __shared__ short Hid[128 * SH];   // [slot][128] hidden chunk bf16 (34 KiB)

    int t = threadIdx.x;
    int p0 = blockIdx.x * 128;

    // ---- gather: 2 threads/slot; q=0 loads src half, q=1 loads dst half ----
    {
        int r = t >> 1, q = t & 1;
        int p = p0 + r;
        int pc = (p < nE) ? p : (nE - 1);
        int s, d;
        if (tmpMode) {
            if (pc < NE_FWD) { s = pc; d = pc + N_NODES; }
            else { int qq = pc - NE_FWD; s = qq + N_NODES; d = qq; }
        } else {
            int e = eidx[pc];
            s = src[e];
            d = dst[e];
        }
        uint4* ao = (uint4*)(Ain + r * SA);
        if (q == 0) {
            const uint4* ps = (const uint4*)(h16 + (size_t)s * D);
#pragma unroll
            for (int i = 0; i < 16; ++i) ao[i] = ps[i];
        } else {
            const uint4* pd = (const uint4*)(h16 + (size_t)d * D);
#pragma unroll
            for (int i = 0; i < 16; ++i) ao[16 + i] = pd[i];
        }
    }
    __syncthreads();

    int w = t >> 6, lane = t & 63;
    int lm = lane & 15, lk = lane >> 4;

    // persistent GEMM2 accumulators: wave w owns out channels [32w, 32w+32) x 128 slots
    f32x4 c2[2][8];
#pragma unroll
    for (int cs = 0; cs < 2; ++cs) {
        int out0 = w * 32 + cs * 16 + lk * 4;
#pragma unroll
        for (int et = 0; et < 8; ++et)
#pragma unroll
            for (int rg = 0; rg < 4; ++rg) c2[cs][et][rg] = b2[out0 + rg];
    }

    // prologue: W1 fragments for chunk 0 into registers
    bf16x8 w1a[8], w1b[8];
#pragma unroll
    for (int kk = 0; kk < 8; ++kk) {
        int ko = kk * 32 + lk * 8;
        w1a[kk] = *(const bf16x8*)(W1T + (size_t)(w * 32 + lm) * 256 + ko);
        w1b[kk] = *(const bf16x8*)(W1T + (size_t)(w * 32 + 16 + lm) * 256 + ko);
    }

    for (int hc = 0; hc < 8; ++hc) {
        // prefetch W2(hc): consumed after the barrier; latency covered by GEMM1 below
        bf16x8 w2a[4], w2b[4];
#pragma unroll
        for (int kk = 0; kk < 4; ++kk) {
            int ko = kk * 32 + lk * 8;
            w2a[kk] = *(const bf16x8*)(W2T + (size_t)(w * 32 + lm) * 1024 + hc * 128 + ko);
            w2b[kk] = *(const bf16x8*)(W2T + (size_t)(w * 32 + 16 + lm) * 1024 + hc * 128 + ko);
        }

        // GEMM1: c1 = Ain @ W1 chunk (W1 fragments already in registers)
        f32x4 c1[2][8];
#pragma unroll
        for (int cs = 0; cs < 2; ++cs) {
            int ch0 = hc * 128 + w * 32 + cs * 16 + lk * 4;
#pragma unroll
            for (int et = 0; et < 8; ++et)
#pragma unroll
                for (int rg = 0; rg < 4; ++rg) c1[cs][et][rg] = b1[ch0 + rg];
        }
#pragma unroll
        for (int kk = 0; kk < 8; ++kk) {
            int ko = kk * 32 + lk * 8;
            bf16x8 bf[8];
#pragma unroll
            for (int et = 0; et < 8; ++et)
                bf[et] = *(const bf16x8*)(Ain + (et * 16 + lm) * SA + ko);
#pragma unroll
            for (int et = 0; et < 8; ++et) {
                c1[0][et] = __builtin_amdgcn_mfma_f32_16x16x32_bf16(w1a[kk], bf[et], c1[0][et], 0, 0, 0);
                c1[1][et] = __builtin_amdgcn_mfma_f32_16x16x32_bf16(w1b[kk], bf[et], c1[1][et], 0, 0, 0);
            }
        }

        // prefetch W1(hc+1): latency covered by Hid-write + barrier + GEMM2
        if (hc < 7) {
#pragma unroll
            for (int kk = 0; kk < 8; ++kk) {
                int ko = kk * 32 + lk * 8;
                w1a[kk] = *(const bf16x8*)(W1T + (size_t)((hc + 1) * 128 + w * 32 + lm) * 256 + ko);
                w1b[kk] = *(const bf16x8*)(W1T + (size_t)((hc + 1) * 128 + w * 32 + 16 + lm) * 256 + ko);
            }
        }

        __syncthreads();   // all waves done reading Hid (GEMM2 of hc-1)
        // write Hid = relu(c1): wave w fills channels [32w, +32) for all 128 slots
#pragma unroll
        for (int cs = 0; cs < 2; ++cs) {
            int ch_in = w * 32 + cs * 16 + lk * 4;
#pragma unroll
            for (int et = 0; et < 8; ++et) {
                int edge = et * 16 + lm;
                short4 sv;
                sv.x = f2bf(fmaxf(c1[cs][et][0], 0.f));
                sv.y = f2bf(fmaxf(c1[cs][et][1], 0.f));
                sv.z = f2bf(fmaxf(c1[cs][et][2], 0.f));
                sv.w = f2bf(fmaxf(c1[cs][et][3], 0.f));
                *(short4*)(Hid + edge * SH + ch_in) = sv;
            }
        }
        __syncthreads();   // Hid(hc) visible

        // GEMM2: accumulate m += Hid(hc) @ W2 chunk (W2 fragments already in registers)
#pragma unroll
        for (int kk = 0; kk < 4; ++kk) {
            int ko = kk * 32 + lk * 8;
            bf16x8 bf[8];
#pragma unroll
            for (int et = 0; et < 8; ++et)
                bf[et] = *(const bf16x8*)(Hid + (et * 16 + lm) * SH + ko);
#pragma unroll
            for (int et = 0; et < 8; ++et) {
                c2[0][et] = __builtin_amdgcn_mfma_f32_16x16x32_bf16(w2a[kk], bf[et], c2[0][et], 0, 0, 0);
                c2[1][et] = __builtin_amdgcn_mfma_f32_16x16x32_bf16(w2b[kk], bf[et], c2[1][et], 0, 0, 0);
            }
        }
    }

    // ---- bf16 store: m[p][ch] = relu(msg) -- dense, fully coalesced per block ----
#pragma unroll
    for (int et = 0; et < 8; ++et) {
        int edge = et * 16 + lm;
        int p = p0 + edge;
        if (p >= nE) continue;
        short* rowp = m + (size_t)p * 128;
#pragma unroll
        for (int cs = 0; cs < 2; ++cs) {
            int out0 = w * 32 + cs * 16 + lk * 4;
            short4 sv;
            sv.x = f2bf(fmaxf(c2[cs][et][0], 0.f));
            sv.y = f2bf(fmaxf(c2[cs][et][1], 0.f));
            sv.z = f2bf(fmaxf(c2[cs][et][2], 0.f));
            sv.w = f2bf(fmaxf(c2[cs][et][3], 0.f));
            *(short4*)(rowp + out0) = sv;
        }
    }
}

// ---------------- fused seg-mean (CSR or temporal) + GRU (MFMA), in place ----------------
// mode 0: rows processed in degree-sorted order (rperm) -> uniform gather trip count
// per wave. mode 1: temporal (affine, rperm=null). 34.8 KB LDS, 4 blocks/CU.
__global__ void __launch_bounds__(256, 4) k_gru_mfma(
    const short* __restrict__ m, const int* __restrict__ rowstart,
    const int* __restrict__ rperm, int mode,
    float* __restrict__ h32, short* __restrict__ h16,
    const short* __restrict__ WT, const short* __restrict__ UT,
    const float* __restrict__ b)
{
    __shared__ short Ax[64 * SK];
    __shared__ short Hx[64 * SK];
    int t = threadIdx.x;
    int r0 = blockIdx.x * 64;

    {
        int r = t >> 2, q = t & 3;
        int slot = r0 + r;
        int sc = (slot < N_TOTAL) ? slot : (N_TOTAL - 1);
        int rowg = rperm ? rperm[sc] : sc;
        const uint4* hp = (const uint4*)(h16 + (size_t)rowg * D);
        uint4* hxo = (uint4*)(Hx + r * SK);
#pragma unroll
        for (int i = 0; i < 4; ++i) hxo[q * 4 + i] = hp[q * 4 + i];

        float acc[32];
#pragma unroll
        for (int i = 0; i < 32; ++i) acc[i] = 0.f;
        int deg = 0;
        if (slot < N_TOTAL) {
            if (mode == 0) {
                int s0 = rowstart[rowg], s1 = rowstart[rowg + 1];
                deg = s1 - s0;
                for (int p = s0; p < s1; ++p) {
                    const uint4* mp = (const uint4*)(m + (size_t)p * 128 + q * 32);
#pragma unroll
                    for (int i = 0; i < 4; ++i) {
                        uint4 v = mp[i];
                        unsigned ua[4] = {v.x, v.y, v.z, v.w};
#pragma unroll
                        for (int j = 0; j < 4; ++j) {
                            acc[i * 8 + 2 * j]     += lo_bf(ua[j]);
                            acc[i * 8 + 2 * j + 1] += hi_bf(ua[j]);
                        }
                    }
                }
            } else {
                if (rowg >= N_NODES) {   // fwd edge e = rowg - N_NODES
                    const uint4* mp = (const uint4*)(m + (size_t)(rowg - N_NODES) * 128 + q * 32);
                    ++deg;
#pragma unroll
                    for (int i = 0; i < 4; ++i) {
                        uint4 v = mp[i];
                        unsigned ua[4] = {v.x, v.y, v.z, v.w};
#pragma unroll
                        for (int j = 0; j < 4; ++j) {
                            acc[i * 8 + 2 * j]     += lo_bf(ua[j]);
                            acc[i * 8 + 2 * j + 1] += hi_bf(ua[j]);
                        }
                    }
                }
                if (rowg < NE_FWD) {     // bwd edge e = NE_FWD + rowg
                    const uint4* mp = (const uint4*)(m + (size_t)(NE_FWD + rowg) * 128 + q * 32);
                    ++deg;
#pragma unroll
                    for (int i = 0; i < 4; ++i) {
                        uint4 v = mp[i];
                        unsigned ua[4] = {v.x, v.y, v.z, v.w};
#pragma unroll
                        for (int j = 0; j < 4; ++j) {
                            acc[i * 8 + 2 * j]     += lo_bf(ua[j]);
                            acc[i * 8 + 2 * j + 1] += hi_bf(ua[j]);
                        }
                    }
                }
            }
        }
        float inv = (deg > 0) ? __builtin_amdgcn_rcpf((float)deg) : 0.f;
        uint4* axp = (uint4*)(Ax + r * SK + q * 32);
#pragma unroll
        for (int i = 0; i < 4; ++i) {
            union { uint4 u; short s[8]; } pk;
#pragma unroll
            for (int j = 0; j < 8; ++j) pk.s[j] = f2bf(acc[i * 8 + j] * inv);
            axp[i] = pk.u;
        }
    }
    __syncthreads();

    int w = t >> 6, lane = t & 63;
    int lm = lane & 15, lk = lane >> 4;

    // row mapping for this thread's 4 output rows (constant across g)
    int slotw[4], roww[4];
#pragma unroll
    for (int rg = 0; rg < 4; ++rg) {
        slotw[rg] = r0 + w * 16 + lk * 4 + rg;
        int sc = (slotw[rg] < N_TOTAL) ? slotw[rg] : (N_TOTAL - 1);
        roww[rg] = rperm ? rperm[sc] : sc;
    }

    for (int g = 0; g < 8; ++g) {
        int ch = g * 16 + lm;

        // prefetch hold = h32[row][ch]: issues before the MFMA cluster (r14)
        float hold[4];
#pragma unroll
        for (int rg = 0; rg < 4; ++rg)
            hold[rg] = h32[(size_t)roww[rg] * D + ch];

        f32x4 cxz, cxr, cxh, chz, chr_, chh;
#pragma unroll
        for (int rg = 0; rg < 4; ++rg) {
            cxz[rg] = b[ch];        chz[rg] = b[384 + ch];
            cxr[rg] = b[128 + ch];  chr_[rg] = b[384 + 128 + ch];
            cxh[rg] = b[256 + ch];  chh[rg] = b[384 + 256 + ch];
        }
#pragma unroll
        for (int kk = 0; kk < 4; ++kk) {
            int ko = kk * 32 + lk * 8;
            bf16x8 ax = *(const bf16x8*)(Ax + (w * 16 + lm) * SK + ko);
            bf16x8 hx = *(const bf16x8*)(Hx + (w * 16 + lm) * SK + ko);
            bf16x8 bz = *(const bf16x8*)(WT + (size_t)(ch) * 128 + ko);
            bf16x8 br = *(const bf16x8*)(WT + (size_t)(128 + ch) * 128 + ko);
            bf16x8 bh = *(const bf16x8*)(WT + (size_t)(256 + ch) * 128 + ko);
            bf16x8 uz = *(const bf16x8*)(UT + (size_t)(ch) * 128 + ko);
            bf16x8 ur = *(const bf16x8*)(UT + (size_t)(128 + ch) * 128 + ko);
            bf16x8 uh = *(const bf16x8*)(UT + (size_t)(256 + ch) * 128 + ko);
            cxz = __builtin_amdgcn_mfma_f32_16x16x32_bf16(ax, bz, cxz, 0, 0, 0);
            cxr = __builtin_amdgcn_mfma_f32_16x16x32_bf16(ax, br, cxr, 0, 0, 0);
            cxh = __builtin_amdgcn_mfma_f32_16x16x32_bf16(ax, bh, cxh, 0, 0, 0);
            chz = __builtin_amdgcn_mfma_f32_16x16x32_bf16(hx, uz, chz, 0, 0, 0);
            chr_ = __builtin_amdgcn_mfma_f32_16x16x32_bf16(hx, ur, chr_, 0, 0, 0);
            chh = __builtin_amdgcn_mfma_f32_16x16x32_bf16(hx, uh, chh, 0, 0, 0);
        }
#pragma unroll
        for (int rg = 0; rg < 4; ++rg) {
            if (slotw[rg] >= N_TOTAL) continue;
            float z = fsigmoid(cxz[rg] + chz[rg]);
            float r_ = fsigmoid(cxr[rg] + chr_[rg]);
            float hcv = ftanh(cxh[rg] + r_ * chh[rg]);
            size_t idx = (size_t)roww[rg] * D + ch;
            float hnew = z * hold[rg] + (1.f - z) * hcv;
            h32[idx] = hnew;
            h16[idx] = f2bf(hnew);
        }
    }
}

// ---------------- generic MFMA GEMM: C = relu(A16 @ B + bias) ----------------
__global__ void __launch_bounds__(256, 4) k_ro_mfma(
    const short* __restrict__ A16, const short* __restrict__ BT,
    const float* __restrict__ bias, float* __restrict__ C32, short* __restrict__ C16,
    int M, int N, int K)
{
    __shared__ short As[64 * SK];
    int t = threadIdx.x;
    int mb = blockIdx.y * 64;
    int nb = blockIdx.x * 128;
    int w = t >> 6, lane = t & 63;
    int lm = lane & 15, lk = lane >> 4;

    f32x4 acc[8];
#pragma unroll
    for (int nt = 0; nt < 8; ++nt) {
        float bv = bias[nb + nt * 16 + lm];
        acc[nt][0] = bv; acc[nt][1] = bv; acc[nt][2] = bv; acc[nt][3] = bv;
    }

    for (int kc = 0; kc < K; kc += 128) {
        __syncthreads();
        {
            int r = t >> 2, q = t & 3;
            int row = mb + r;
            int rc = (row < M) ? row : (M - 1);
            const uint4* ap = (const uint4*)(A16 + (size_t)rc * K + kc);
            uint4* ao = (uint4*)(As + r * SK);
#pragma unroll
            for (int i = 0; i < 4; ++i) ao[i * 4 + q] = ap[i * 4 + q];
        }
        __syncthreads();
#pragma unroll
        for (int kk = 0; kk < 4; ++kk) {
            int ko = kk * 32 + lk * 8;
            bf16x8 a = *(const bf16x8*)(As + (w * 16 + lm) * SK + ko);
#pragma unroll
            for (int nt = 0; nt < 8; ++nt) {
                bf16x8 bfr = *(const bf16x8*)(BT + (size_t)(nb + nt * 16 + lm) * K + kc + ko);
                acc[nt] = __builtin_amdgcn_mfma_f32_16x16x32_bf16(a, bfr, acc[nt], 0, 0, 0);
            }
        }
    }
#pragma unroll
    for (int nt = 0; nt < 8; ++nt) {
        int col = nb + nt * 16 + lm;
#pragma unroll
        for (int rg = 0; rg < 4; ++rg) {
            int row = mb + w * 16 + lk * 4 + rg;
            if (row >= M) continue;
            float v = fmaxf(acc[nt][rg], 0.f);
            if (C32) C32[(size_t)row * N + col] = v;
            if (C16) C16[(size_t)row * N + col] = f2bf(v);
        }
    }
}

// ---------------- final 512x10 logits + softmax ----------------
__global__ void __launch_bounds__(64) k_logits_softmax(
    const float* __restrict__ r2, const float* __restrict__ W3,
    const float* __restrict__ b3, float* __restrict__ out)
{
    int row = blockIdx.x;
    int t = threadIdx.x;
    float p[10];
#pragma unroll
    for (int j = 0; j < 10; ++j) p[j] = 0.f;
    for (int k = t; k < 512; k += 64) {
        float v = r2[(size_t)row * 512 + k];
#pragma unroll
        for (int j = 0; j < 10; ++j) p[j] += v * W3[k * 10 + j];
    }
#pragma unroll
    for (int j = 0; j < 10; ++j) {
        float s = p[j];
        for (int off = 32; off > 0; off >>= 1) s += __shfl_down(s, off);
        p[j] = s;
    }
    if (t == 0) {
        float mx = -1e30f;
#pragma unroll
        for (int j = 0; j < 10; ++j) { p[j] += b3[j]; mx = fmaxf(mx, p[j]); }
        float sum = 0.f;
#pragma unroll
        for (int j = 0; j < 10; ++j) { p[j] = __expf(p[j] - mx); sum += p[j]; }
        float inv = 1.f / sum;
#pragma unroll
        for (int j = 0; j < 10; ++j) out[(size_t)row * 10 + j] = p[j] * inv;
    }
}

extern "C" void kernel_launch(void* const* d_in, const int* in_sizes, int n_in,
                              void* d_out, int out_size, void* d_ws, size_t ws_size,
                              hipStream_t stream)
{
    const int*   ie    = (const int*)d_in[0];
    const int*   nodes = (const int*)d_in[1];
    const float* embed = (const float*)d_in[2];
    const float* mW1   = (const float*)d_in[3];
    const float* mb1   = (const float*)d_in[4];
    const float* mW2   = (const float*)d_in[5];
    const float* mb2   = (const float*)d_in[6];
    const float* giW   = (const float*)d_in[7];
    const float* giU   = (const float*)d_in[8];
    const float* gib   = (const float*)d_in[9];
    const float* gtW   = (const float*)d_in[10];
    const float* gtU   = (const float*)d_in[11];
    const float* gtb   = (const float*)d_in[12];
    const float* rW1   = (const float*)d_in[13];
    const float* rb1   = (const float*)d_in[14];
    const float* rW2   = (const float*)d_in[15];
    const float* rb2   = (const float*)d_in[16];
    const float* rW3   = (const float*)d_in[17];
    const float* rb3   = (const float*)d_in[18];
    float* out = (float*)d_out;

    char* ws = (char*)d_ws;
    size_t off = 0;
    auto alloc = [&](size_t bytes) {
        void* p = ws + off;
        off += (bytes + 255) & ~(size_t)255;
        return p;
    };
    float* h32   = (float*)alloc((size_t)N_TOTAL * D * 4);
    short* h16   = (short*)alloc((size_t)N_TOTAL * D * 2);
    short* m     = (short*)alloc((size_t)NE_INT * 128 * 2);   // edge messages, bf16
    int*   icnt  = (int*)alloc((size_t)N_TOTAL * 4);
    int*   rowst = (int*)alloc((size_t)(N_TOTAL + 1) * 4);
    int*   btot  = (int*)alloc(256 * 4);
    int*   curs  = (int*)alloc((size_t)N_TOTAL * 4);
    int*   eidx  = (int*)alloc((size_t)NE_INT * 4);
    int*   srcA  = (int*)alloc((size_t)NE_INT * 4);
    int*   dstA  = (int*)alloc((size_t)NE_INT * 4);
    int*   dhist = (int*)alloc(64 * 4);
    int*   dcur  = (int*)alloc(64 * 4);
    int*   rperm = (int*)alloc((size_t)N_TOTAL * 4);
    short* mW1T  = (short*)alloc((size_t)HID * 256 * 2);
    short* mW2T  = (short*)alloc((size_t)D * HID * 2);
    short* giWT  = (short*)alloc((size_t)384 * D * 2);
    short* giUT  = (short*)alloc((size_t)384 * D * 2);
    short* gtWT  = (short*)alloc((size_t)384 * D * 2);
    short* gtUT  = (short*)alloc((size_t)384 * D * 2);
    short* rW1T  = (short*)alloc((size_t)HID * D * 2);
    short* rW2T  = (short*)alloc((size_t)512 * HID * 2);
    short* r1_16 = (short*)alloc((size_t)N_NODES * HID * 2);
    float* r2_32 = (float*)alloc((size_t)N_NODES * 512 * 4);

    // weight repack: 8 transposes in ONE launch
    {
        TcvtArgs a;
        a.in[0] = mW1; a.out[0] = mW1T; a.K[0] = 256; a.N[0] = HID;
        a.in[1] = mW2; a.out[1] = mW2T; a.K[1] = HID; a.N[1] = D;
        a.in[2] = giW; a.out[2] = giWT; a.K[2] = D;   a.N[2] = 384;
        a.in[3] = giU; a.out[3] = giUT; a.K[3] = D;   a.N[3] = 384;
        a.in[4] = gtW; a.out[4] = gtWT; a.K[4] = D;   a.N[4] = 384;
        a.in[5] = gtU; a.out[5] = gtUT; a.K[5] = D;   a.N[5] = 384;
        a.in[6] = rW1; a.out[6] = rW1T; a.K[6] = D;   a.N[6] = HID;
        a.in[7] = rW2; a.out[7] = rW2T; a.K[7] = HID; a.N[7] = 512;
        int total = 256 * HID + HID * D + 4 * (D * 384) + D * HID + HID * 512;
        k_tcvt8<<<(total + 255) / 256, 256, 0, stream>>>(a);
    }

    // init + CSR build (int edges static across iterations)
    hipMemsetAsync(icnt, 0, (size_t)N_TOTAL * 4, stream);
    hipMemsetAsync(dhist, 0, 64 * 4, stream);
    k_init_h<<<(N_TOTAL * D + 255) / 256, 256, 0, stream>>>(nodes, embed, h32, h16);
    k_build_int_edges<<<(NE_INT + 255) / 256, 256, 0, stream>>>(ie, srcA, dstA, icnt);
    int nb = (N_TOTAL + SCAN_B - 1) / SCAN_B;   // 196
    k_scan_partial<<<nb, SCAN_B, 0, stream>>>(icnt, rowst, btot, N_TOTAL);
    k_scan_block<<<1, SCAN_B, 0, stream>>>(btot, nb);
    k_scan_add<<<nb, SCAN_B, 0, stream>>>(rowst, btot, curs, N_TOTAL, NE_INT);
    k_fill_csr<<<(NE_INT + 255) / 256, 256, 0, stream>>>(dstA, NE_INT, curs, eidx);
    // degree-sorted row permutation for gru mode 0 (low-contention counting sort)
    k_deg_hist<<<(N_TOTAL + 255) / 256, 256, 0, stream>>>(rowst, dhist);
    k_deg_scan<<<1, 64, 0, stream>>>(dhist, dcur);
    k_deg_scatter<<<(N_TOTAL + 255) / 256, 256, 0, stream>>>(rowst, dcur, rperm);

    int gmsgA = (NE_INT + 127) / 128;   // 1024
    int gmsgT = (NE_TMP + 127) / 128;   // 704
    int ggru = (N_TOTAL + 63) / 64;     // 782
    for (int it = 0; it < 2; ++it) {
        // int pass: CSR-ordered processing -> dense m store, dst-local gather
        k_msg_mfma<<<gmsgA, 256, 0, stream>>>(h16, eidx, srcA, dstA, NE_INT, 0, mW1T, mb1, mW2T, mb2, m);
        k_gru_mfma<<<ggru, 256, 0, stream>>>(m, rowst, rperm, 0, h32, h16, giWT, giUT, gib);

        // temporal pass: affine src/dst in-kernel, identity slot order
        k_msg_mfma<<<gmsgT, 256, 0, stream>>>(h16, (const int*)nullptr, (const int*)nullptr,
                                              (const int*)nullptr, NE_TMP, 1, mW1T, mb1, mW2T, mb2, m);
        k_gru_mfma<<<ggru, 256, 0, stream>>>(m, rowst, (const int*)nullptr, 1, h32, h16, gtWT, gtUT, gtb);
    }

    // readout
    dim3 g1(HID / 128, (N_NODES + 63) / 64);
    k_ro_mfma<<<g1, 256, 0, stream>>>(h16, rW1T, rb1, (float*)nullptr, r1_16, N_NODES, HID, D);
    dim3 g2(512 / 128, (N_NODES + 63) / 64);
    k_ro_mfma<<<g2, 256, 0, stream>>>(r1_16, rW2T, rb2, r2_32, (short*)nullptr, N_NODES, 512, HID);
    k_logits_softmax<<<N_NODES, 64, 0, stream>>>(r2_32, rW3, rb3, out);
}

// Round 17
// 1196.033 us; speedup vs baseline: 1.3993x; 1.0184x over previous
//
#include <hip/hip_runtime.h>
#include <math.h>

#define D 128
#define N_NODES 5000
#define WINDOW 10
#define N_TOTAL 50000
#define NE_INT 131072
#define NE_TMP 90000
#define NE_FWD (N_TOTAL - N_NODES)   // 45000
#define HID 1024

typedef short bf16x8 __attribute__((ext_vector_type(8)));
typedef float f32x4 __attribute__((ext_vector_type(4)));

#define SA 264   // Ain LDS row stride in shorts (256 + 8 pad)
#define SH 136   // 128 + 8 pad
#define SK 136   // 128 + 8 pad
#define SCAN_B 256

static __device__ __forceinline__ short f2bf(float f) {
    union { float f; unsigned u; } v; v.f = f;
    unsigned r = v.u + 0x7fffu + ((v.u >> 16) & 1u);   // RNE
    return (short)(r >> 16);
}
static __device__ __forceinline__ float bf2f(short s) {
    union { unsigned u; float f; } v;
    v.u = ((unsigned)(unsigned short)s) << 16;
    return v.f;
}
static __device__ __forceinline__ float lo_bf(unsigned u) {
    union { unsigned u; float f; } v; v.u = u << 16; return v.f;
}
static __device__ __forceinline__ float hi_bf(unsigned u) {
    union { unsigned u; float f; } v; v.u = u & 0xffff0000u; return v.f;
}

// ---- fast transcendentals (r13): v_exp_f32 via __expf + v_rcp_f32 ----
static __device__ __forceinline__ float fsigmoid(float x) {
    return __builtin_amdgcn_rcpf(1.f + __expf(-x));   // exp overflow benign
}
static __device__ __forceinline__ float ftanh(float x) {
    float xc = fminf(fmaxf(x, -20.f), 20.f);
    float t = __expf(2.f * xc);
    return (t - 1.f) * __builtin_amdgcn_rcpf(t + 1.f);
}

// ---------------- merged weight transpose + cvt: 8 segments in one launch ----------------
struct TcvtArgs {
    const float* in[8];
    short* out[8];
    int K[8];
    int N[8];
};
__global__ void k_tcvt8(TcvtArgs a) {
    int i = blockIdx.x * blockDim.x + threadIdx.x;
#pragma unroll
    for (int s = 0; s < 8; ++s) {
        int sz = a.K[s] * a.N[s];
        if (i < sz) {
            int n = i / a.K[s], k = i - n * a.K[s];
            a.out[s][i] = f2bf(a.in[s][(size_t)k * a.N[s] + n]);
            return;
        }
        i -= sz;
    }
}

// ---------------- init h ----------------
__global__ void k_init_h(const int* __restrict__ nodes, const float* __restrict__ embed,
                         float* __restrict__ h32, short* __restrict__ h16) {
    int i = blockIdx.x * blockDim.x + threadIdx.x;
    if (i >= N_TOTAL * D) return;
    int row = i >> 7;
    int c = i & 127;
    int n = nodes[row / WINDOW];
    float v = embed[n * D + c];
    h32[i] = v;
    h16[i] = f2bf(v);
}

// ---------------- edge builder (int only; temporal edges computed affinely in-kernel) ----------------
__global__ void k_build_int_edges(const int* __restrict__ ie, int* __restrict__ src,
                                  int* __restrict__ dst, int* __restrict__ icnt) {
    int e = blockIdx.x * blockDim.x + threadIdx.x;
    if (e >= NE_INT) return;
    int t = ie[e * 3 + 0], a = ie[e * 3 + 1], b = ie[e * 3 + 2];
    int d = t * N_NODES + b;
    src[e] = t * N_NODES + a;
    dst[e] = d;
    atomicAdd(&icnt[d], 1);
}

// ---------------- 3-kernel exclusive scan over icnt[N_TOTAL] -> rowstart ----------------
__global__ void k_scan_partial(const int* __restrict__ cnt, int* __restrict__ rowstart,
                               int* __restrict__ btot, int n) {
    __shared__ int s[SCAN_B];
    int tid = threadIdx.x;
    int i = blockIdx.x * SCAN_B + tid;
    int v = (i < n) ? cnt[i] : 0;
    s[tid] = v;
    __syncthreads();
    for (int off = 1; off < SCAN_B; off <<= 1) {
        int x = (tid >= off) ? s[tid - off] : 0;
        __syncthreads();
        s[tid] += x;
        __syncthreads();
    }
    if (i < n) rowstart[i] = s[tid] - v;   // block-local exclusive
    if (tid == SCAN_B - 1) btot[blockIdx.x] = s[tid];
}

__global__ void k_scan_block(int* __restrict__ btot, int nb) {
    __shared__ int s[SCAN_B];
    int tid = threadIdx.x;
    int v = (tid < nb) ? btot[tid] : 0;
    s[tid] = v;
    __syncthreads();
    for (int off = 1; off < SCAN_B; off <<= 1) {
        int x = (tid >= off) ? s[tid - off] : 0;
        __syncthreads();
        s[tid] += x;
        __syncthreads();
    }
    if (tid < nb) btot[tid] = s[tid] - v;  // exclusive block offsets
}

__global__ void k_scan_add(int* __restrict__ rowstart, const int* __restrict__ btot,
                           int* __restrict__ cursor, int n, int total) {
    int i = blockIdx.x * blockDim.x + threadIdx.x;
    if (i < n) {
        int v = rowstart[i] + btot[i >> 8];
        rowstart[i] = v;
        cursor[i] = v;
    }
    if (i == 0) rowstart[n] = total;
}

// eidx[p] = edge at CSR slot p (dst-sorted). msg processes slots in order -> dense m store.
__global__ void k_fill_csr(const int* __restrict__ dst, int nE, int* __restrict__ cursor,
                           int* __restrict__ eidx) {
    int e = blockIdx.x * blockDim.x + threadIdx.x;
    if (e >= nE) return;
    int p = atomicAdd(&cursor[dst[e]], 1);
    eidx[p] = e;
}

// ---------------- fused message MLP (MFMA), 128-slot blocks, W register-prefetch ----------------
// r12/r13 proven structure (183us int): CSR-ordered slots + W1/W2 register prefetch
// (W2(hc) issued before GEMM1, W1(hc+1) after GEMM1 -> latency covered by MFMA work).
__global__ void __launch_bounds__(256, 1) k_msg_mfma(
    const short* __restrict__ h16, const int* __restrict__ eidx,
    const int* __restrict__ src, const int* __restrict__ dst,
    int nE, int tmpMode,
    const short* __restrict__ W1T, const float* __restrict__ b1,
    const short* __restrict__ W2T, const float* __restrict__ b2,
    short* __restrict__ m)
{
    __shared__ short Ain[128 * SA];   // [slot][0:256) = [h[src] | h[dst]] bf16 (66 KiB)
    __shared__ short Hid[128 * SH];   // [slot][128] hidden chunk bf16 (34 KiB)

    int t = threadIdx.x;
    int p0 = blockIdx.x * 128;

    // ---- gather: 2 threads/slot; q=0 loads src half, q=1 loads dst half ----
    {
        int r = t >> 1, q = t & 1;
        int p = p0 + r;
        int pc = (p < nE) ? p : (nE - 1);
        int s, d;
        if (tmpMode) {
            if (pc < NE_FWD) { s = pc; d = pc + N_NODES; }
            else { int qq = pc - NE_FWD; s = qq + N_NODES; d = qq; }
        } else {
            int e = eidx[pc];
            s = src[e];
            d = dst[e];
        }
        uint4* ao = (uint4*)(Ain + r * SA);
        if (q == 0) {
            const uint4* ps = (const uint4*)(h16 + (size_t)s * D);
#pragma unroll
            for (int i = 0; i < 16; ++i) ao[i] = ps[i];
        } else {
            const uint4* pd = (const uint4*)(h16 + (size_t)d * D);
#pragma unroll
            for (int i = 0; i < 16; ++i) ao[16 + i] = pd[i];
        }
    }
    __syncthreads();

    int w = t >> 6, lane = t & 63;
    int lm = lane & 15, lk = lane >> 4;

    // persistent GEMM2 accumulators: wave w owns out channels [32w, 32w+32) x 128 slots
    f32x4 c2[2][8];
#pragma unroll
    for (int cs = 0; cs < 2; ++cs) {
        int out0 = w * 32 + cs * 16 + lk * 4;
#pragma unroll
        for (int et = 0; et < 8; ++et)
#pragma unroll
            for (int rg = 0; rg < 4; ++rg) c2[cs][et][rg] = b2[out0 + rg];
    }

    // prologue: W1 fragments for chunk 0 into registers
    bf16x8 w1a[8], w1b[8];
#pragma unroll
    for (int kk = 0; kk < 8; ++kk) {
        int ko = kk * 32 + lk * 8;
        w1a[kk] = *(const bf16x8*)(W1T + (size_t)(w * 32 + lm) * 256 + ko);
        w1b[kk] = *(const bf16x8*)(W1T + (size_t)(w * 32 + 16 + lm) * 256 + ko);
    }

    for (int hc = 0; hc < 8; ++hc) {
        // prefetch W2(hc): consumed after the barrier; latency covered by GEMM1 below
        bf16x8 w2a[4], w2b[4];
#pragma unroll
        for (int kk = 0; kk < 4; ++kk) {
            int ko = kk * 32 + lk * 8;
            w2a[kk] = *(const bf16x8*)(W2T + (size_t)(w * 32 + lm) * 1024 + hc * 128 + ko);
            w2b[kk] = *(const bf16x8*)(W2T + (size_t)(w * 32 + 16 + lm) * 1024 + hc * 128 + ko);
        }

        // GEMM1: c1 = Ain @ W1 chunk (W1 fragments already in registers)
        f32x4 c1[2][8];
#pragma unroll
        for (int cs = 0; cs < 2; ++cs) {
            int ch0 = hc * 128 + w * 32 + cs * 16 + lk * 4;
#pragma unroll
            for (int et = 0; et < 8; ++et)
#pragma unroll
                for (int rg = 0; rg < 4; ++rg) c1[cs][et][rg] = b1[ch0 + rg];
        }
#pragma unroll
        for (int kk = 0; kk < 8; ++kk) {
            int ko = kk * 32 + lk * 8;
            bf16x8 bf[8];
#pragma unroll
            for (int et = 0; et < 8; ++et)
                bf[et] = *(const bf16x8*)(Ain + (et * 16 + lm) * SA + ko);
#pragma unroll
            for (int et = 0; et < 8; ++et) {
                c1[0][et] = __builtin_amdgcn_mfma_f32_16x16x32_bf16(w1a[kk], bf[et], c1[0][et], 0, 0, 0);
                c1[1][et] = __builtin_amdgcn_mfma_f32_16x16x32_bf16(w1b[kk], bf[et], c1[1][et], 0, 0, 0);
            }
        }

        // prefetch W1(hc+1): latency covered by Hid-write + barrier + GEMM2
        if (hc < 7) {
#pragma unroll
            for (int kk = 0; kk < 8; ++kk) {
                int ko = kk * 32 + lk * 8;
                w1a[kk] = *(const bf16x8*)(W1T + (size_t)((hc + 1) * 128 + w * 32 + lm) * 256 + ko);
                w1b[kk] = *(const bf16x8*)(W1T + (size_t)((hc + 1) * 128 + w * 32 + 16 + lm) * 256 + ko);
            }
        }

        __syncthreads();   // all waves done reading Hid (GEMM2 of hc-1)
        // write Hid = relu(c1): wave w fills channels [32w, +32) for all 128 slots
#pragma unroll
        for (int cs = 0; cs < 2; ++cs) {
            int ch_in = w * 32 + cs * 16 + lk * 4;
#pragma unroll
            for (int et = 0; et < 8; ++et) {
                int edge = et * 16 + lm;
                short4 sv;
                sv.x = f2bf(fmaxf(c1[cs][et][0], 0.f));
                sv.y = f2bf(fmaxf(c1[cs][et][1], 0.f));
                sv.z = f2bf(fmaxf(c1[cs][et][2], 0.f));
                sv.w = f2bf(fmaxf(c1[cs][et][3], 0.f));
                *(short4*)(Hid + edge * SH + ch_in) = sv;
            }
        }
        __syncthreads();   // Hid(hc) visible

        // GEMM2: accumulate m += Hid(hc) @ W2 chunk (W2 fragments already in registers)
#pragma unroll
        for (int kk = 0; kk < 4; ++kk) {
            int ko = kk * 32 + lk * 8;
            bf16x8 bf[8];
#pragma unroll
            for (int et = 0; et < 8; ++et)
                bf[et] = *(const bf16x8*)(Hid + (et * 16 + lm) * SH + ko);
#pragma unroll
            for (int et = 0; et < 8; ++et) {
                c2[0][et] = __builtin_amdgcn_mfma_f32_16x16x32_bf16(w2a[kk], bf[et], c2[0][et], 0, 0, 0);
                c2[1][et] = __builtin_amdgcn_mfma_f32_16x16x32_bf16(w2b[kk], bf[et], c2[1][et], 0, 0, 0);
            }
        }
    }

    // ---- bf16 store: m[p][ch] = relu(msg) -- dense, fully coalesced per block ----
#pragma unroll
    for (int et = 0; et < 8; ++et) {
        int edge = et * 16 + lm;
        int p = p0 + edge;
        if (p >= nE) continue;
        short* rowp = m + (size_t)p * 128;
#pragma unroll
        for (int cs = 0; cs < 2; ++cs) {
            int out0 = w * 32 + cs * 16 + lk * 4;
            short4 sv;
            sv.x = f2bf(fmaxf(c2[cs][et][0], 0.f));
            sv.y = f2bf(fmaxf(c2[cs][et][1], 0.f));
            sv.z = f2bf(fmaxf(c2[cs][et][2], 0.f));
            sv.w = f2bf(fmaxf(c2[cs][et][3], 0.f));
            *(short4*)(rowp + out0) = sv;
        }
    }
}

// ---------------- fused seg-mean (CSR or temporal) + GRU (MFMA), in place ----------------
// mode 0: m CSR-ordered contiguous. mode 1: temporal (affine). 34.8 KB LDS, 4 blocks/CU.
// r14: per-g prefetch of the h32 "hold" values before each MFMA cluster.
__global__ void __launch_bounds__(256, 4) k_gru_mfma(
    const short* __restrict__ m, const int* __restrict__ rowstart, int mode,
    float* __restrict__ h32, short* __restrict__ h16,
    const short* __restrict__ WT, const short* __restrict__ UT,
    const float* __restrict__ b)
{
    __shared__ short Ax[64 * SK];
    __shared__ short Hx[64 * SK];
    int t = threadIdx.x;
    int r0 = blockIdx.x * 64;

    {
        int r = t >> 2, q = t & 3;
        int row = r0 + r;
        int rc = (row < N_TOTAL) ? row : (N_TOTAL - 1);
        const uint4* hp = (const uint4*)(h16 + (size_t)rc * D);
        uint4* hxo = (uint4*)(Hx + r * SK);
#pragma unroll
        for (int i = 0; i < 4; ++i) hxo[q * 4 + i] = hp[q * 4 + i];

        float acc[32];
#pragma unroll
        for (int i = 0; i < 32; ++i) acc[i] = 0.f;
        int deg = 0;
        if (row < N_TOTAL) {
            if (mode == 0) {
                int s0 = rowstart[row], s1 = rowstart[row + 1];
                deg = s1 - s0;
                for (int p = s0; p < s1; ++p) {
                    const uint4* mp = (const uint4*)(m + (size_t)p * 128 + q * 32);
#pragma unroll
                    for (int i = 0; i < 4; ++i) {
                        uint4 v = mp[i];
                        unsigned ua[4] = {v.x, v.y, v.z, v.w};
#pragma unroll
                        for (int j = 0; j < 4; ++j) {
                            acc[i * 8 + 2 * j]     += lo_bf(ua[j]);
                            acc[i * 8 + 2 * j + 1] += hi_bf(ua[j]);
                        }
                    }
                }
            } else {
                if (row >= N_NODES) {   // fwd edge e = row - N_NODES
                    const uint4* mp = (const uint4*)(m + (size_t)(row - N_NODES) * 128 + q * 32);
                    ++deg;
#pragma unroll
                    for (int i = 0; i < 4; ++i) {
                        uint4 v = mp[i];
                        unsigned ua[4] = {v.x, v.y, v.z, v.w};
#pragma unroll
                        for (int j = 0; j < 4; ++j) {
                            acc[i * 8 + 2 * j]     += lo_bf(ua[j]);
                            acc[i * 8 + 2 * j + 1] += hi_bf(ua[j]);
                        }
                    }
                }
                if (row < NE_FWD) {     // bwd edge e = NE_FWD + row
                    const uint4* mp = (const uint4*)(m + (size_t)(NE_FWD + row) * 128 + q * 32);
                    ++deg;
#pragma unroll
                    for (int i = 0; i < 4; ++i) {
                        uint4 v = mp[i];
                        unsigned ua[4] = {v.x, v.y, v.z, v.w};
#pragma unroll
                        for (int j = 0; j < 4; ++j) {
                            acc[i * 8 + 2 * j]     += lo_bf(ua[j]);
                            acc[i * 8 + 2 * j + 1] += hi_bf(ua[j]);
                        }
                    }
                }
            }
        }
        float inv = (deg > 0) ? __builtin_amdgcn_rcpf((float)deg) : 0.f;
        uint4* axp = (uint4*)(Ax + r * SK + q * 32);
#pragma unroll
        for (int i = 0; i < 4; ++i) {
            union { uint4 u; short s[8]; } pk;
#pragma unroll
            for (int j = 0; j < 8; ++j) pk.s[j] = f2bf(acc[i * 8 + j] * inv);
            axp[i] = pk.u;
        }
    }
    __syncthreads();

    int w = t >> 6, lane = t & 63;
    int lm = lane & 15, lk = lane >> 4;

    for (int g = 0; g < 8; ++g) {
        int ch = g * 16 + lm;

        // prefetch hold = h32[row][ch]: issues before the MFMA cluster,
        // consumed only in the epilogue below (latency fully covered)
        float hold[4];
#pragma unroll
        for (int rg = 0; rg < 4; ++rg) {
            int row = r0 + w * 16 + lk * 4 + rg;
            int rcl = (row < N_TOTAL) ? row : (N_TOTAL - 1);
            hold[rg] = h32[(size_t)rcl * D + ch];
        }

        f32x4 cxz, cxr, cxh, chz, chr_, chh;
#pragma unroll
        for (int rg = 0; rg < 4; ++rg) {
            cxz[rg] = b[ch];        chz[rg] = b[384 + ch];
            cxr[rg] = b[128 + ch];  chr_[rg] = b[384 + 128 + ch];
            cxh[rg] = b[256 + ch];  chh[rg] = b[384 + 256 + ch];
        }
#pragma unroll
        for (int kk = 0; kk < 4; ++kk) {
            int ko = kk * 32 + lk * 8;
            bf16x8 ax = *(const bf16x8*)(Ax + (w * 16 + lm) * SK + ko);
            bf16x8 hx = *(const bf16x8*)(Hx + (w * 16 + lm) * SK + ko);
            bf16x8 bz = *(const bf16x8*)(WT + (size_t)(ch) * 128 + ko);
            bf16x8 br = *(const bf16x8*)(WT + (size_t)(128 + ch) * 128 + ko);
            bf16x8 bh = *(const bf16x8*)(WT + (size_t)(256 + ch) * 128 + ko);
            bf16x8 uz = *(const bf16x8*)(UT + (size_t)(ch) * 128 + ko);
            bf16x8 ur = *(const bf16x8*)(UT + (size_t)(128 + ch) * 128 + ko);
            bf16x8 uh = *(const bf16x8*)(UT + (size_t)(256 + ch) * 128 + ko);
            cxz = __builtin_amdgcn_mfma_f32_16x16x32_bf16(ax, bz, cxz, 0, 0, 0);
            cxr = __builtin_amdgcn_mfma_f32_16x16x32_bf16(ax, br, cxr, 0, 0, 0);
            cxh = __builtin_amdgcn_mfma_f32_16x16x32_bf16(ax, bh, cxh, 0, 0, 0);
            chz = __builtin_amdgcn_mfma_f32_16x16x32_bf16(hx, uz, chz, 0, 0, 0);
            chr_ = __builtin_amdgcn_mfma_f32_16x16x32_bf16(hx, ur, chr_, 0, 0, 0);
            chh = __builtin_amdgcn_mfma_f32_16x16x32_bf16(hx, uh, chh, 0, 0, 0);
        }
#pragma unroll
        for (int rg = 0; rg < 4; ++rg) {
            int row = r0 + w * 16 + lk * 4 + rg;
            if (row >= N_TOTAL) continue;
            float z = fsigmoid(cxz[rg] + chz[rg]);
            float r_ = fsigmoid(cxr[rg] + chr_[rg]);
            float hcv = ftanh(cxh[rg] + r_ * chh[rg]);
            size_t idx = (size_t)row * D + ch;
            float hnew = z * hold[rg] + (1.f - z) * hcv;
            h32[idx] = hnew;
            h16[idx] = f2bf(hnew);
        }
    }
}

// ---------------- generic MFMA GEMM: C = relu(A16 @ B + bias) ----------------
__global__ void __launch_bounds__(256, 4) k_ro_mfma(
    const short* __restrict__ A16, const short* __restrict__ BT,
    const float* __restrict__ bias, float* __restrict__ C32, short* __restrict__ C16,
    int M, int N, int K)
{
    __shared__ short As[64 * SK];
    int t = threadIdx.x;
    int mb = blockIdx.y * 64;
    int nb = blockIdx.x * 128;
    int w = t >> 6, lane = t & 63;
    int lm = lane & 15, lk = lane >> 4;

    f32x4 acc[8];
#pragma unroll
    for (int nt = 0; nt < 8; ++nt) {
        float bv = bias[nb + nt * 16 + lm];
        acc[nt][0] = bv; acc[nt][1] = bv; acc[nt][2] = bv; acc[nt][3] = bv;
    }

    for (int kc = 0; kc < K; kc += 128) {
        __syncthreads();
        {
            int r = t >> 2, q = t & 3;
            int row = mb + r;
            int rc = (row < M) ? row : (M - 1);
            const uint4* ap = (const uint4*)(A16 + (size_t)rc * K + kc);
            uint4* ao = (uint4*)(As + r * SK);
#pragma unroll
            for (int i = 0; i < 4; ++i) ao[i * 4 + q] = ap[i * 4 + q];
        }
        __syncthreads();
#pragma unroll
        for (int kk = 0; kk < 4; ++kk) {
            int ko = kk * 32 + lk * 8;
            bf16x8 a = *(const bf16x8*)(As + (w * 16 + lm) * SK + ko);
#pragma unroll
            for (int nt = 0; nt < 8; ++nt) {
                bf16x8 bfr = *(const bf16x8*)(BT + (size_t)(nb + nt * 16 + lm) * K + kc + ko);
                acc[nt] = __builtin_amdgcn_mfma_f32_16x16x32_bf16(a, bfr, acc[nt], 0, 0, 0);
            }
        }
    }
#pragma unroll
    for (int nt = 0; nt < 8; ++nt) {
        int col = nb + nt * 16 + lm;
#pragma unroll
        for (int rg = 0; rg < 4; ++rg) {
            int row = mb + w * 16 + lk * 4 + rg;
            if (row >= M) continue;
            float v = fmaxf(acc[nt][rg], 0.f);
            if (C32) C32[(size_t)row * N + col] = v;
            if (C16) C16[(size_t)row * N + col] = f2bf(v);
        }
    }
}

// ---------------- final 512x10 logits + softmax ----------------
__global__ void __launch_bounds__(64) k_logits_softmax(
    const float* __restrict__ r2, const float* __restrict__ W3,
    const float* __restrict__ b3, float* __restrict__ out)
{
    int row = blockIdx.x;
    int t = threadIdx.x;
    float p[10];
#pragma unroll
    for (int j = 0; j < 10; ++j) p[j] = 0.f;
    for (int k = t; k < 512; k += 64) {
        float v = r2[(size_t)row * 512 + k];
#pragma unroll
        for (int j = 0; j < 10; ++j) p[j] += v * W3[k * 10 + j];
    }
#pragma unroll
    for (int j = 0; j < 10; ++j) {
        float s = p[j];
        for (int off = 32; off > 0; off >>= 1) s += __shfl_down(s, off);
        p[j] = s;
    }
    if (t == 0) {
        float mx = -1e30f;
#pragma unroll
        for (int j = 0; j < 10; ++j) { p[j] += b3[j]; mx = fmaxf(mx, p[j]); }
        float sum = 0.f;
#pragma unroll
        for (int j = 0; j < 10; ++j) { p[j] = __expf(p[j] - mx); sum += p[j]; }
        float inv = 1.f / sum;
#pragma unroll
        for (int j = 0; j < 10; ++j) out[(size_t)row * 10 + j] = p[j] * inv;
    }
}

extern "C" void kernel_launch(void* const* d_in, const int* in_sizes, int n_in,
                              void* d_out, int out_size, void* d_ws, size_t ws_size,
                              hipStream_t stream)
{
    const int*   ie    = (const int*)d_in[0];
    const int*   nodes = (const int*)d_in[1];
    const float* embed = (const float*)d_in[2];
    const float* mW1   = (const float*)d_in[3];
    const float* mb1   = (const float*)d_in[4];
    const float* mW2   = (const float*)d_in[5];
    const float* mb2   = (const float*)d_in[6];
    const float* giW   = (const float*)d_in[7];
    const float* giU   = (const float*)d_in[8];
    const float* gib   = (const float*)d_in[9];
    const float* gtW   = (const float*)d_in[10];
    const float* gtU   = (const float*)d_in[11];
    const float* gtb   = (const float*)d_in[12];
    const float* rW1   = (const float*)d_in[13];
    const float* rb1   = (const float*)d_in[14];
    const float* rW2   = (const float*)d_in[15];
    const float* rb2   = (const float*)d_in[16];
    const float* rW3   = (const float*)d_in[17];
    const float* rb3   = (const float*)d_in[18];
    float* out = (float*)d_out;

    char* ws = (char*)d_ws;
    size_t off = 0;
    auto alloc = [&](size_t bytes) {
        void* p = ws + off;
        off += (bytes + 255) & ~(size_t)255;
        return p;
    };
    float* h32   = (float*)alloc((size_t)N_TOTAL * D * 4);
    short* h16   = (short*)alloc((size_t)N_TOTAL * D * 2);
    short* m     = (short*)alloc((size_t)NE_INT * 128 * 2);   // edge messages, bf16
    int*   icnt  = (int*)alloc((size_t)N_TOTAL * 4);
    int*   rowst = (int*)alloc((size_t)(N_TOTAL + 1) * 4);
    int*   btot  = (int*)alloc(256 * 4);
    int*   curs  = (int*)alloc((size_t)N_TOTAL * 4);
    int*   eidx  = (int*)alloc((size_t)NE_INT * 4);
    int*   srcA  = (int*)alloc((size_t)NE_INT * 4);
    int*   dstA  = (int*)alloc((size_t)NE_INT * 4);
    short* mW1T  = (short*)alloc((size_t)HID * 256 * 2);
    short* mW2T  = (short*)alloc((size_t)D * HID * 2);
    short* giWT  = (short*)alloc((size_t)384 * D * 2);
    short* giUT  = (short*)alloc((size_t)384 * D * 2);
    short* gtWT  = (short*)alloc((size_t)384 * D * 2);
    short* gtUT  = (short*)alloc((size_t)384 * D * 2);
    short* rW1T  = (short*)alloc((size_t)HID * D * 2);
    short* rW2T  = (short*)alloc((size_t)512 * HID * 2);
    short* r1_16 = (short*)alloc((size_t)N_NODES * HID * 2);
    float* r2_32 = (float*)alloc((size_t)N_NODES * 512 * 4);

    // weight repack: 8 transposes in ONE launch
    {
        TcvtArgs a;
        a.in[0] = mW1; a.out[0] = mW1T; a.K[0] = 256; a.N[0] = HID;
        a.in[1] = mW2; a.out[1] = mW2T; a.K[1] = HID; a.N[1] = D;
        a.in[2] = giW; a.out[2] = giWT; a.K[2] = D;   a.N[2] = 384;
        a.in[3] = giU; a.out[3] = giUT; a.K[3] = D;   a.N[3] = 384;
        a.in[4] = gtW; a.out[4] = gtWT; a.K[4] = D;   a.N[4] = 384;
        a.in[5] = gtU; a.out[5] = gtUT; a.K[5] = D;   a.N[5] = 384;
        a.in[6] = rW1; a.out[6] = rW1T; a.K[6] = D;   a.N[6] = HID;
        a.in[7] = rW2; a.out[7] = rW2T; a.K[7] = HID; a.N[7] = 512;
        int total = 256 * HID + HID * D + 4 * (D * 384) + D * HID + HID * 512;
        k_tcvt8<<<(total + 255) / 256, 256, 0, stream>>>(a);
    }

    // init + CSR build (int edges static across iterations)
    hipMemsetAsync(icnt, 0, (size_t)N_TOTAL * 4, stream);
    k_init_h<<<(N_TOTAL * D + 255) / 256, 256, 0, stream>>>(nodes, embed, h32, h16);
    k_build_int_edges<<<(NE_INT + 255) / 256, 256, 0, stream>>>(ie, srcA, dstA, icnt);
    int nb = (N_TOTAL + SCAN_B - 1) / SCAN_B;   // 196
    k_scan_partial<<<nb, SCAN_B, 0, stream>>>(icnt, rowst, btot, N_TOTAL);
    k_scan_block<<<1, SCAN_B, 0, stream>>>(btot, nb);
    k_scan_add<<<nb, SCAN_B, 0, stream>>>(rowst, btot, curs, N_TOTAL, NE_INT);
    k_fill_csr<<<(NE_INT + 255) / 256, 256, 0, stream>>>(dstA, NE_INT, curs, eidx);

    int gmsgA = (NE_INT + 127) / 128;   // 1024
    int gmsgT = (NE_TMP + 127) / 128;   // 704
    int ggru = (N_TOTAL + 63) / 64;     // 782
    for (int it = 0; it < 2; ++it) {
        // int pass: CSR-ordered processing -> dense m store, dst-local gather
        k_msg_mfma<<<gmsgA, 256, 0, stream>>>(h16, eidx, srcA, dstA, NE_INT, 0, mW1T, mb1, mW2T, mb2, m);
        k_gru_mfma<<<ggru, 256, 0, stream>>>(m, rowst, 0, h32, h16, giWT, giUT, gib);

        // temporal pass: affine src/dst in-kernel, identity slot order
        k_msg_mfma<<<gmsgT, 256, 0, stream>>>(h16, (const int*)nullptr, (const int*)nullptr,
                                              (const int*)nullptr, NE_TMP, 1, mW1T, mb1, mW2T, mb2, m);
        k_gru_mfma<<<ggru, 256, 0, stream>>>(m, rowst, 1, h32, h16, gtWT, gtUT, gtb);
    }

    // readout
    dim3 g1(HID / 128, (N_NODES + 63) / 64);
    k_ro_mfma<<<g1, 256, 0, stream>>>(h16, rW1T, rb1, (float*)nullptr, r1_16, N_NODES, HID, D);
    dim3 g2(512 / 128, (N_NODES + 63) / 64);
    k_ro_mfma<<<g2, 256, 0, stream>>>(r1_16, rW2T, rb2, r2_32, (short*)nullptr, N_NODES, 512, HID);
    k_logits_softmax<<<N_NODES, 64, 0, stream>>>(r2_32, rW3, rb3, out);
}